// Round 10
// baseline (247.709 us; speedup 1.0000x reference)
//
#include <hip/hip_runtime.h>
#include <hip/hip_bf16.h>
#include <hip/hip_fp16.h>
#include <stdint.h>

typedef __bf16 bf16_t;
typedef __bf16 bf16x8 __attribute__((ext_vector_type(8)));
typedef float f32x4 __attribute__((ext_vector_type(4)));

typedef __attribute__((address_space(1))) void gv_t;
typedef __attribute__((address_space(3))) void lv_t;

__device__ inline unsigned short f2bf_bits(float f) {
  uint32_t u = __float_as_uint(f);
  u += 0x7FFFu + ((u >> 16) & 1u);   // RNE
  return (unsigned short)(u >> 16);
}
__device__ inline bf16_t f2bf(float f) {
  unsigned short h = f2bf_bits(f);
  return __builtin_bit_cast(bf16_t, h);
}

__device__ inline void storeC(float* p, float v) { *p = v; }
__device__ inline void storeC(bf16_t* p, float v) { *p = f2bf(v); }
__device__ inline void storeC(__half* p, float v) { *p = __float2half(v); }

// ---------------------------------------------------------------------------
// fp32 -> bf16 conversion for x, Wq, Wk (packed together), Wv
// ---------------------------------------------------------------------------
__global__ __launch_bounds__(256)
void convert_all(const float* __restrict__ x, const float* __restrict__ wq,
                 const float* __restrict__ wk, const float* __restrict__ wv,
                 bf16_t* __restrict__ xb, bf16_t* __restrict__ wqkb,
                 bf16_t* __restrict__ wvb)
{
  const int64_t NX = 8192LL * 1024, NW = 1024LL * 1024;
  const int64_t total4 = (NX + 3 * NW) >> 2;
  for (int64_t i = (int64_t)blockIdx.x * blockDim.x + threadIdx.x; i < total4;
       i += (int64_t)gridDim.x * blockDim.x) {
    int64_t e = i << 2;
    const float* src; bf16_t* dst; int64_t off;
    if (e < NX)               { src = x;  dst = xb;         off = e; }
    else if (e < NX + NW)     { src = wq; dst = wqkb;       off = e - NX; }
    else if (e < NX + 2 * NW) { src = wk; dst = wqkb + NW;  off = e - NX - NW; }
    else                      { src = wv; dst = wvb;        off = e - NX - 2 * NW; }
    float4 f = *(const float4*)(src + off);
    uint32_t lo = ((uint32_t)f2bf_bits(f.y) << 16) | f2bf_bits(f.x);
    uint32_t hi = ((uint32_t)f2bf_bits(f.w) << 16) | f2bf_bits(f.z);
    *(uint2*)(dst + off) = make_uint2(lo, hi);
  }
}

// ---------------------------------------------------------------------------
// 128x128 bf16 GEMM, 1-barrier-per-K-tile loop (R8 choreography), BK=64,
// 4 waves (2x2), per-wave 64x64 out = acc[4][4] frags of 16x16x32.
// LDS 64 KiB (As/Bs [2 dbuf][128][64] bf16) -> 2 blocks/CU co-resident:
// R10's single variable vs R8's 256^2 tile. Rationale: R8's per-tile
// vmcnt(0)+s_barrier stalls the WHOLE CU at 1 block/CU; with 2 blocks the
// sibling block's MFMA bursts cover the drain/barrier window (m114
// implicit overlap). Same XOR swizzle (source slot ^(srow&7), read
// ^((lane&7)<<4)); same 1-barrier WAR/RAW discipline as R8.
// blockIdx.z: split-K chunk (A += z*za_off cols, B += z*zb_off cols,
// z=0 -> C0, z=1 -> C1). B batch: Bb = B + (bm/bm_per_batch)*b_batch_stride.
// ---------------------------------------------------------------------------
template <typename OUT_T, typename OUT2_T>
__global__ __launch_bounds__(256, 2)
void gemm128(const bf16_t* __restrict__ A, const bf16_t* __restrict__ B,
             OUT_T* __restrict__ C0, OUT2_T* __restrict__ C1,
             int K, int lda, int ldb, int ldc,
             int64_t b_batch_stride, int bm_per_batch,
             int64_t za_off, int64_t zb_off)
{
  __shared__ bf16_t As[2][128][64];
  __shared__ bf16_t Bs[2][128][64];

  const int tid  = threadIdx.x;
  const int wid  = tid >> 6;     // 0..3
  const int lane = tid & 63;
  const int wm = wid >> 1;       // 0..1 -> 64-row panel
  const int wn = wid & 1;        // 0..1 -> 64-col panel
  const int64_t bm = blockIdx.x;
  const int64_t bn = blockIdx.y;
  const int z = blockIdx.z;

  const bf16_t* Ap = A + (int64_t)z * za_off;
  const bf16_t* Bp = B + (bm / bm_per_batch) * b_batch_stride
                       + (int64_t)z * zb_off;

  // staging: one gload instr (per wave) covers 32 rows (256 thr x 16 B).
  // thread -> row tid>>3 (0..31), slot tid&7; source slot pre-swizzled.
  const int srow  = tid >> 3;
  const int sslot = (tid & 7) ^ (srow & 7);
  const int64_t lda64 = lda, ldb64 = ldb;
  const bf16_t* Ag = Ap + (bm * 128 + srow) * lda64 + sslot * 8;
  const bf16_t* Bg = Bp + (bn * 128 + srow) * ldb64 + sslot * 8;

  // q-th 32-row quarter of tile t -> LDS buf (linear dest; wave w owns
  // rows q*32 + w*8 .. +8)
  auto stageA = [&](int buf, int t, int q) {
    const bf16_t* src = Ag + (int64_t)(q * 32) * lda64 + t * 64;
    char* dst = (char*)&As[buf][0][0] + (q * 32 + wid * 8) * 128;
    __builtin_amdgcn_global_load_lds((const gv_t*)src, (lv_t*)dst, 16, 0, 0);
  };
  auto stageB = [&](int buf, int t, int q) {
    const bf16_t* src = Bg + (int64_t)(q * 32) * ldb64 + t * 64;
    char* dst = (char*)&Bs[buf][0][0] + (q * 32 + wid * 8) * 128;
    __builtin_amdgcn_global_load_lds((const gv_t*)src, (lv_t*)dst, 16, 0, 0);
  };

  // fragment read coords (swizzled): row&7 == lane&7 for all frags
  const int frow   = lane & 15;
  const int fcol16 = lane >> 4;               // 0..3
  const int xorv   = (lane & 7) << 4;
  const int ck0 = (fcol16 * 16) ^ xorv;       // kk=0 (k 0..31) byte col
  const int ck1 = (64 + fcol16 * 16) ^ xorv;  // kk=1 (k 32..63)
  const int arowb = (wm * 64 + frow) * 128;   // byte row base in As
  const int browb = (wn * 64 + frow) * 128;   // byte row base in Bs

  f32x4 acc[4][4];
  #pragma unroll
  for (int m = 0; m < 4; m++)
    #pragma unroll
    for (int n = 0; n < 4; n++) acc[m][n] = f32x4{0.f, 0.f, 0.f, 0.f};

  const int NT = K >> 6;

  // prologue: stage T0; wait; barrier
  stageA(0, 0, 0); stageA(0, 0, 1); stageA(0, 0, 2); stageA(0, 0, 3);
  stageB(0, 0, 0); stageB(0, 0, 1); stageB(0, 0, 2); stageB(0, 0, 3);
  asm volatile("s_waitcnt vmcnt(0)" ::: "memory");
  __builtin_amdgcn_s_barrier();
  __builtin_amdgcn_sched_barrier(0);

  bf16x8 a[4][2], bb[4][2];

  for (int g = 0; g < NT; ++g) {
    const int buf = g & 1;
    const char* lA = (const char*)&As[buf][0][0];
    const char* lB = (const char*)&Bs[buf][0][0];

    // ---- all 16 frag reads, k0 frags first (k1 drains under k0 MFMAs) ----
    #pragma unroll
    for (int m = 0; m < 4; m++)
      a[m][0] = *(const bf16x8*)(lA + arowb + m * 2048 + ck0);
    #pragma unroll
    for (int n = 0; n < 4; n++)
      bb[n][0] = *(const bf16x8*)(lB + browb + n * 2048 + ck0);
    #pragma unroll
    for (int m = 0; m < 4; m++)
      a[m][1] = *(const bf16x8*)(lA + arowb + m * 2048 + ck1);
    #pragma unroll
    for (int n = 0; n < 4; n++)
      bb[n][1] = *(const bf16x8*)(lB + browb + n * 2048 + ck1);

    // ---- stage next K-tile into the other buffer (WAR-safe per R8) ----
    if (g + 1 < NT) {
      stageA(buf ^ 1, g + 1, 0); stageA(buf ^ 1, g + 1, 1);
      stageA(buf ^ 1, g + 1, 2); stageA(buf ^ 1, g + 1, 3);
      stageB(buf ^ 1, g + 1, 0); stageB(buf ^ 1, g + 1, 1);
      stageB(buf ^ 1, g + 1, 2); stageB(buf ^ 1, g + 1, 3);
    }

    // ---- 32 MFMAs; compiler-counted lgkm waits overlap reads/compute ----
    __builtin_amdgcn_s_setprio(1);
    #pragma unroll
    for (int k = 0; k < 2; k++)
      #pragma unroll
      for (int m = 0; m < 4; m++)
        #pragma unroll
        for (int n = 0; n < 4; n++)
          acc[m][n] = __builtin_amdgcn_mfma_f32_16x16x32_bf16(
              a[m][k], bb[n][k], acc[m][n], 0, 0, 0);
    __builtin_amdgcn_s_setprio(0);

    // ---- next tile resident + own reads consumed -> single barrier ----
    asm volatile("s_waitcnt vmcnt(0)" ::: "memory");
    __builtin_amdgcn_s_barrier();
    __builtin_amdgcn_sched_barrier(0);
  }

  // epilogue: C/D layout col=lane&15, row=(lane>>4)*4+j
  const int crow = (lane >> 4) * 4;
  const int ccol = lane & 15;
  if (z == 0) {
    #pragma unroll
    for (int m = 0; m < 4; m++)
      #pragma unroll
      for (int n = 0; n < 4; n++)
        #pragma unroll
        for (int j = 0; j < 4; j++) {
          int64_t row = bm * 128 + wm * 64 + m * 16 + crow + j;
          int64_t col = bn * 128 + wn * 64 + n * 16 + ccol;
          storeC(&C0[row * (int64_t)ldc + col], acc[m][n][j]);
        }
  } else {
    #pragma unroll
    for (int m = 0; m < 4; m++)
      #pragma unroll
      for (int n = 0; n < 4; n++)
        #pragma unroll
        for (int j = 0; j < 4; j++) {
          int64_t row = bm * 128 + wm * 64 + m * 16 + crow + j;
          int64_t col = bn * 128 + wn * 64 + n * 16 + ccol;
          storeC(&C1[row * (int64_t)ldc + col], acc[m][n][j]);
        }
  }
}

// ---------------------------------------------------------------------------
// Row softmax IN PLACE: fp16 raw scores [rows x 4096] -> normalized bf16 P.
// ---------------------------------------------------------------------------
__global__ __launch_bounds__(256)
void softmax_rows(__half* __restrict__ SP)
{
  const int64_t row = blockIdx.x;
  __half* s = SP + row * 4096;
  bf16_t* p = (bf16_t*)s;
  const int tid = threadIdx.x;
  const float scale = 0.03125f;  // 1/sqrt(1024)

  float v[16];
  float vmax = -3.4e38f;
  #pragma unroll
  for (int i = 0; i < 4; i++) {
    uint2 raw = *(const uint2*)(s + i * 1024 + tid * 4);
    __half2 h01 = __builtin_bit_cast(__half2, raw.x);
    __half2 h23 = __builtin_bit_cast(__half2, raw.y);
    float2 f01 = __half22float2(h01);
    float2 f23 = __half22float2(h23);
    v[i * 4 + 0] = f01.x * scale;
    v[i * 4 + 1] = f01.y * scale;
    v[i * 4 + 2] = f23.x * scale;
    v[i * 4 + 3] = f23.y * scale;
    vmax = fmaxf(vmax, fmaxf(fmaxf(v[i*4+0], v[i*4+1]),
                             fmaxf(v[i*4+2], v[i*4+3])));
  }
  #pragma unroll
  for (int o = 32; o > 0; o >>= 1) vmax = fmaxf(vmax, __shfl_xor(vmax, o));
  __shared__ float redm[4];
  __shared__ float reds[4];
  if ((tid & 63) == 0) redm[tid >> 6] = vmax;
  __syncthreads();
  vmax = fmaxf(fmaxf(redm[0], redm[1]), fmaxf(redm[2], redm[3]));

  float lsum = 0.f;
  #pragma unroll
  for (int i = 0; i < 16; i++) {
    v[i] = __expf(v[i] - vmax);
    lsum += v[i];
  }
  #pragma unroll
  for (int o = 32; o > 0; o >>= 1) lsum += __shfl_xor(lsum, o);
  if ((tid & 63) == 0) reds[tid >> 6] = lsum;
  __syncthreads();
  lsum = (reds[0] + reds[1]) + (reds[2] + reds[3]);
  const float inv = 1.0f / lsum;

  #pragma unroll
  for (int i = 0; i < 4; i++) {
    uint32_t lo = ((uint32_t)f2bf_bits(v[i*4+1] * inv) << 16) | f2bf_bits(v[i*4+0] * inv);
    uint32_t hi = ((uint32_t)f2bf_bits(v[i*4+3] * inv) << 16) | f2bf_bits(v[i*4+2] * inv);
    *(uint2*)(p + i * 1024 + tid * 4) = make_uint2(lo, hi);
  }
}

// ---------------------------------------------------------------------------
// out[i] += (float)partial_fp16[i]  (split-K reduce)
// ---------------------------------------------------------------------------
__global__ __launch_bounds__(256)
void addk_h4(float4* __restrict__ o, const uint2* __restrict__ a, int64_t n4)
{
  for (int64_t i = (int64_t)blockIdx.x * blockDim.x + threadIdx.x; i < n4;
       i += (int64_t)gridDim.x * blockDim.x) {
    float4 x = o[i];
    uint2 raw = a[i];
    __half2 h01 = __builtin_bit_cast(__half2, raw.x);
    __half2 h23 = __builtin_bit_cast(__half2, raw.y);
    float2 f01 = __half22float2(h01);
    float2 f23 = __half22float2(h23);
    x.x += f01.x; x.y += f01.y; x.z += f23.x; x.w += f23.y;
    o[i] = x;
  }
}

// ---------------------------------------------------------------------------
// ws layout (112 MiB):
//   [0,   64M): S/P fp16->bf16 [8192 x 4096]
//               overlapped early: xb [0,16M), wqkb [16M,20M), wvb [20M,22M)
//   [64M, 96M): qk bf16 [8192 x 2048] (Q|K); dead after S -> reused as
//               PV fp16 split-K partial pk16 [8192 x 1024] (16 MiB)
//   [96M,112M): vt bf16 [1024 x 8192]
// ---------------------------------------------------------------------------
extern "C" void kernel_launch(void* const* d_in, const int* in_sizes, int n_in,
                              void* d_out, int out_size, void* d_ws, size_t ws_size,
                              hipStream_t stream) {
  const float* x  = (const float*)d_in[0];
  const float* wq = (const float*)d_in[1];
  const float* wk = (const float*)d_in[2];
  const float* wv = (const float*)d_in[3];
  float* out = (float*)d_out;

  char* ws = (char*)d_ws;
  bf16_t* xb   = (bf16_t*)ws;
  bf16_t* wqkb = (bf16_t*)(ws + (16LL << 20));
  bf16_t* wvb  = (bf16_t*)(ws + (20LL << 20));
  __half* S    = (__half*)ws;
  bf16_t* qk   = (bf16_t*)(ws + (64LL << 20));
  __half* pk16 = (__half*)(ws + (64LL << 20));  // PV split-K partial (16 MiB)
  bf16_t* vt   = (bf16_t*)(ws + (96LL << 20));

  const int NO_BATCH = 1 << 30;

  convert_all<<<2048, 256, 0, stream>>>(x, wq, wk, wv, xb, wqkb, wvb);

  // qk[8192 x 2048] = xb * wqkb^T
  gemm128<bf16_t, bf16_t><<<dim3(64, 16, 1), 256, 0, stream>>>(
      xb, wqkb, qk, qk, 1024, 1024, 1024, 2048, 0, NO_BATCH, 0, 0);

  // vt[1024 x 8192] = wvb * xb^T
  gemm128<bf16_t, bf16_t><<<dim3(8, 64, 1), 256, 0, stream>>>(
      wvb, xb, vt, vt, 1024, 1024, 1024, 8192, 0, NO_BATCH, 0, 0);

  // S[8192 x 4096] = Q * K_b^T (raw fp16), batch b = bm/32
  gemm128<__half, __half><<<dim3(64, 32, 1), 256, 0, stream>>>(
      qk, qk + 1024, S, S, 1024, 2048, 2048, 4096, 4096LL * 2048, 32, 0, 0);

  softmax_rows<<<8192, 256, 0, stream>>>(S);

  // out[8192 x 1024] = P * V_b^T, split-K (z=0 -> out f32, z=1 -> pk16 fp16)
  gemm128<float, __half><<<dim3(64, 8, 2), 256, 0, stream>>>(
      (const bf16_t*)S, vt, out, pk16, 2048, 4096, 8192, 1024,
      4096, 32, 2048, 2048);

  addk_h4<<<2048, 256, 0, stream>>>((float4*)out, (const uint2*)pk16,
                                    8192LL * 1024 / 4);
}

// Round 11
// 244.483 us; speedup vs baseline: 1.0132x; 1.0132x over previous
//
#include <hip/hip_runtime.h>
#include <hip/hip_bf16.h>
#include <hip/hip_fp16.h>
#include <stdint.h>

typedef __bf16 bf16_t;
typedef __bf16 bf16x8 __attribute__((ext_vector_type(8)));
typedef float f32x4 __attribute__((ext_vector_type(4)));

typedef __attribute__((address_space(1))) void gv_t;
typedef __attribute__((address_space(3))) void lv_t;

__device__ inline unsigned short f2bf_bits(float f) {
  uint32_t u = __float_as_uint(f);
  u += 0x7FFFu + ((u >> 16) & 1u);   // RNE
  return (unsigned short)(u >> 16);
}
__device__ inline bf16_t f2bf(float f) {
  unsigned short h = f2bf_bits(f);
  return __builtin_bit_cast(bf16_t, h);
}

__device__ inline void storeC(float* p, float v) { *p = v; }
__device__ inline void storeC(bf16_t* p, float v) { *p = f2bf(v); }
__device__ inline void storeC(__half* p, float v) { *p = __float2half(v); }

// ---------------------------------------------------------------------------
// fp32 -> bf16 conversion for x, Wq, Wk (packed together), Wv
// ---------------------------------------------------------------------------
__global__ __launch_bounds__(256)
void convert_all(const float* __restrict__ x, const float* __restrict__ wq,
                 const float* __restrict__ wk, const float* __restrict__ wv,
                 bf16_t* __restrict__ xb, bf16_t* __restrict__ wqkb,
                 bf16_t* __restrict__ wvb)
{
  const int64_t NX = 8192LL * 1024, NW = 1024LL * 1024;
  const int64_t total4 = (NX + 3 * NW) >> 2;
  for (int64_t i = (int64_t)blockIdx.x * blockDim.x + threadIdx.x; i < total4;
       i += (int64_t)gridDim.x * blockDim.x) {
    int64_t e = i << 2;
    const float* src; bf16_t* dst; int64_t off;
    if (e < NX)               { src = x;  dst = xb;         off = e; }
    else if (e < NX + NW)     { src = wq; dst = wqkb;       off = e - NX; }
    else if (e < NX + 2 * NW) { src = wk; dst = wqkb + NW;  off = e - NX - NW; }
    else                      { src = wv; dst = wvb;        off = e - NX - 2 * NW; }
    float4 f = *(const float4*)(src + off);
    uint32_t lo = ((uint32_t)f2bf_bits(f.y) << 16) | f2bf_bits(f.x);
    uint32_t hi = ((uint32_t)f2bf_bits(f.w) << 16) | f2bf_bits(f.z);
    *(uint2*)(dst + off) = make_uint2(lo, hi);
  }
}

// ---------------------------------------------------------------------------
// 128x128 bf16 GEMM, 1-barrier-per-K-tile (R8 choreography) — kept for Vt.
// ---------------------------------------------------------------------------
template <typename OUT_T, typename OUT2_T>
__global__ __launch_bounds__(256, 2)
void gemm128(const bf16_t* __restrict__ A, const bf16_t* __restrict__ B,
             OUT_T* __restrict__ C0, OUT2_T* __restrict__ C1,
             int K, int lda, int ldb, int ldc,
             int64_t b_batch_stride, int bm_per_batch,
             int64_t za_off, int64_t zb_off)
{
  __shared__ bf16_t As[2][128][64];
  __shared__ bf16_t Bs[2][128][64];

  const int tid  = threadIdx.x;
  const int wid  = tid >> 6;
  const int lane = tid & 63;
  const int wm = wid >> 1;
  const int wn = wid & 1;
  const int64_t bm = blockIdx.x;
  const int64_t bn = blockIdx.y;
  const int z = blockIdx.z;

  const bf16_t* Ap = A + (int64_t)z * za_off;
  const bf16_t* Bp = B + (bm / bm_per_batch) * b_batch_stride
                       + (int64_t)z * zb_off;

  const int srow  = tid >> 3;
  const int sslot = (tid & 7) ^ (srow & 7);
  const int64_t lda64 = lda, ldb64 = ldb;
  const bf16_t* Ag = Ap + (bm * 128 + srow) * lda64 + sslot * 8;
  const bf16_t* Bg = Bp + (bn * 128 + srow) * ldb64 + sslot * 8;

  auto stageA = [&](int buf, int t, int q) {
    const bf16_t* src = Ag + (int64_t)(q * 32) * lda64 + t * 64;
    char* dst = (char*)&As[buf][0][0] + (q * 32 + wid * 8) * 128;
    __builtin_amdgcn_global_load_lds((const gv_t*)src, (lv_t*)dst, 16, 0, 0);
  };
  auto stageB = [&](int buf, int t, int q) {
    const bf16_t* src = Bg + (int64_t)(q * 32) * ldb64 + t * 64;
    char* dst = (char*)&Bs[buf][0][0] + (q * 32 + wid * 8) * 128;
    __builtin_amdgcn_global_load_lds((const gv_t*)src, (lv_t*)dst, 16, 0, 0);
  };

  const int frow   = lane & 15;
  const int fcol16 = lane >> 4;
  const int xorv   = (lane & 7) << 4;
  const int ck0 = (fcol16 * 16) ^ xorv;
  const int ck1 = (64 + fcol16 * 16) ^ xorv;
  const int arowb = (wm * 64 + frow) * 128;
  const int browb = (wn * 64 + frow) * 128;

  f32x4 acc[4][4];
  #pragma unroll
  for (int m = 0; m < 4; m++)
    #pragma unroll
    for (int n = 0; n < 4; n++) acc[m][n] = f32x4{0.f, 0.f, 0.f, 0.f};

  const int NT = K >> 6;

  stageA(0, 0, 0); stageA(0, 0, 1); stageA(0, 0, 2); stageA(0, 0, 3);
  stageB(0, 0, 0); stageB(0, 0, 1); stageB(0, 0, 2); stageB(0, 0, 3);
  asm volatile("s_waitcnt vmcnt(0)" ::: "memory");
  __builtin_amdgcn_s_barrier();
  __builtin_amdgcn_sched_barrier(0);

  bf16x8 a[4][2], bb[4][2];

  for (int g = 0; g < NT; ++g) {
    const int buf = g & 1;
    const char* lA = (const char*)&As[buf][0][0];
    const char* lB = (const char*)&Bs[buf][0][0];

    #pragma unroll
    for (int m = 0; m < 4; m++)
      a[m][0] = *(const bf16x8*)(lA + arowb + m * 2048 + ck0);
    #pragma unroll
    for (int n = 0; n < 4; n++)
      bb[n][0] = *(const bf16x8*)(lB + browb + n * 2048 + ck0);
    #pragma unroll
    for (int m = 0; m < 4; m++)
      a[m][1] = *(const bf16x8*)(lA + arowb + m * 2048 + ck1);
    #pragma unroll
    for (int n = 0; n < 4; n++)
      bb[n][1] = *(const bf16x8*)(lB + browb + n * 2048 + ck1);

    if (g + 1 < NT) {
      stageA(buf ^ 1, g + 1, 0); stageA(buf ^ 1, g + 1, 1);
      stageA(buf ^ 1, g + 1, 2); stageA(buf ^ 1, g + 1, 3);
      stageB(buf ^ 1, g + 1, 0); stageB(buf ^ 1, g + 1, 1);
      stageB(buf ^ 1, g + 1, 2); stageB(buf ^ 1, g + 1, 3);
    }

    __builtin_amdgcn_s_setprio(1);
    #pragma unroll
    for (int k = 0; k < 2; k++)
      #pragma unroll
      for (int m = 0; m < 4; m++)
        #pragma unroll
        for (int n = 0; n < 4; n++)
          acc[m][n] = __builtin_amdgcn_mfma_f32_16x16x32_bf16(
              a[m][k], bb[n][k], acc[m][n], 0, 0, 0);
    __builtin_amdgcn_s_setprio(0);

    asm volatile("s_waitcnt vmcnt(0)" ::: "memory");
    __builtin_amdgcn_s_barrier();
    __builtin_amdgcn_sched_barrier(0);
  }

  const int crow = (lane >> 4) * 4;
  const int ccol = lane & 15;
  if (z == 0) {
    #pragma unroll
    for (int m = 0; m < 4; m++)
      #pragma unroll
      for (int n = 0; n < 4; n++)
        #pragma unroll
        for (int j = 0; j < 4; j++) {
          int64_t row = bm * 128 + wm * 64 + m * 16 + crow + j;
          int64_t col = bn * 128 + wn * 64 + n * 16 + ccol;
          storeC(&C0[row * (int64_t)ldc + col], acc[m][n][j]);
        }
  } else {
    #pragma unroll
    for (int m = 0; m < 4; m++)
      #pragma unroll
      for (int n = 0; n < 4; n++)
        #pragma unroll
        for (int j = 0; j < 4; j++) {
          int64_t row = bm * 128 + wm * 64 + m * 16 + crow + j;
          int64_t col = bn * 128 + wn * 64 + n * 16 + ccol;
          storeC(&C1[row * (int64_t)ldc + col], acc[m][n][j]);
        }
  }
}

// ---------------------------------------------------------------------------
// FAT 256x256 bf16 GEMM (R11): 4 waves (2x2), per-wave 128x128 = acc[8][8].
// BK=64, LDS 128 KiB (As/Bs [2][256][64]), same XOR swizzle, same R8
// 1-barrier choreography. Rationale: halves LDS-reads per FLOP (per-wave
// reads ~ Mw+Nw for Mw*Nw FLOPs) so the MFMA burst (128 MFMA ~2060 cyc)
// dominates and the k1 reads + staging drain UNDER it via compiler-counted
// lgkm — within-wave overlap, no barrier choreography needed.
// VGPR: acc 256 + frags 128 + addr ~25 = ~410 (< 450 spill line, 1 wave/EU).
// blockIdx.z split-K: z=0 -> C0, z=1 -> C1 (fp16 partial).
// ---------------------------------------------------------------------------
template <typename OUT_T, typename OUT2_T>
__global__ __launch_bounds__(256, 1)
void gemm_fat(const bf16_t* __restrict__ A, const bf16_t* __restrict__ B,
              OUT_T* __restrict__ C0, OUT2_T* __restrict__ C1,
              int K, int lda, int ldb, int ldc,
              int64_t b_batch_stride, int bm_per_batch,
              int64_t za_off, int64_t zb_off)
{
  __shared__ bf16_t As[2][256][64];
  __shared__ bf16_t Bs[2][256][64];

  const int tid  = threadIdx.x;
  const int wid  = tid >> 6;     // 0..3
  const int lane = tid & 63;
  const int wm = wid >> 1;       // 0..1 -> 128-row panel
  const int wn = wid & 1;        // 0..1 -> 128-col panel
  const int64_t bm = blockIdx.x;
  const int64_t bn = blockIdx.y;
  const int z = blockIdx.z;

  const bf16_t* Ap = A + (int64_t)z * za_off;
  const bf16_t* Bp = B + (bm / bm_per_batch) * b_batch_stride
                       + (int64_t)z * zb_off;

  // staging: 256 thr x 16B = one 32-row slab per instr; 8 instrs per operand
  const int srow  = tid >> 3;          // 0..31
  const int sslot = (tid & 7) ^ (srow & 7);
  const int64_t lda64 = lda, ldb64 = ldb;
  const bf16_t* Ag = Ap + (bm * 256 + srow) * lda64 + sslot * 8;
  const bf16_t* Bg = Bp + (bn * 256 + srow) * ldb64 + sslot * 8;

  auto stageA = [&](int buf, int t, int q) {
    const bf16_t* src = Ag + (int64_t)(q * 32) * lda64 + t * 64;
    char* dst = (char*)&As[buf][0][0] + (q * 32 + wid * 8) * 128;
    __builtin_amdgcn_global_load_lds((const gv_t*)src, (lv_t*)dst, 16, 0, 0);
  };
  auto stageB = [&](int buf, int t, int q) {
    const bf16_t* src = Bg + (int64_t)(q * 32) * ldb64 + t * 64;
    char* dst = (char*)&Bs[buf][0][0] + (q * 32 + wid * 8) * 128;
    __builtin_amdgcn_global_load_lds((const gv_t*)src, (lv_t*)dst, 16, 0, 0);
  };

  // fragment read coords (swizzled): row&7 == lane&7 for all frags
  const int frow   = lane & 15;
  const int fcol16 = lane >> 4;
  const int xorv   = (lane & 7) << 4;
  const int ck0 = (fcol16 * 16) ^ xorv;
  const int ck1 = (64 + fcol16 * 16) ^ xorv;
  const int arowb = (wm * 128 + frow) * 128;
  const int browb = (wn * 128 + frow) * 128;

  f32x4 acc[8][8];
  #pragma unroll
  for (int m = 0; m < 8; m++)
    #pragma unroll
    for (int n = 0; n < 8; n++) acc[m][n] = f32x4{0.f, 0.f, 0.f, 0.f};

  const int NT = K >> 6;

  // prologue: stage T0; wait; barrier
  #pragma unroll
  for (int q = 0; q < 8; q++) stageA(0, 0, q);
  #pragma unroll
  for (int q = 0; q < 8; q++) stageB(0, 0, q);
  asm volatile("s_waitcnt vmcnt(0)" ::: "memory");
  __builtin_amdgcn_s_barrier();
  __builtin_amdgcn_sched_barrier(0);

  bf16x8 a[8][2], bb[8][2];

  for (int g = 0; g < NT; ++g) {
    const int buf = g & 1;
    const char* lA = (const char*)&As[buf][0][0];
    const char* lB = (const char*)&Bs[buf][0][0];

    // ---- 32 frag reads, k0 first (k1 drains under k0 MFMA burst) ----
    #pragma unroll
    for (int m = 0; m < 8; m++)
      a[m][0] = *(const bf16x8*)(lA + arowb + m * 2048 + ck0);
    #pragma unroll
    for (int n = 0; n < 8; n++)
      bb[n][0] = *(const bf16x8*)(lB + browb + n * 2048 + ck0);
    #pragma unroll
    for (int m = 0; m < 8; m++)
      a[m][1] = *(const bf16x8*)(lA + arowb + m * 2048 + ck1);
    #pragma unroll
    for (int n = 0; n < 8; n++)
      bb[n][1] = *(const bf16x8*)(lB + browb + n * 2048 + ck1);

    // ---- stage next K-tile into the other buffer (WAR-safe per R8) ----
    if (g + 1 < NT) {
      #pragma unroll
      for (int q = 0; q < 8; q++) stageA(buf ^ 1, g + 1, q);
      #pragma unroll
      for (int q = 0; q < 8; q++) stageB(buf ^ 1, g + 1, q);
    }

    // ---- 128 MFMAs; counted lgkm waits overlap reads/stage under burst ----
    __builtin_amdgcn_s_setprio(1);
    #pragma unroll
    for (int k = 0; k < 2; k++)
      #pragma unroll
      for (int m = 0; m < 8; m++)
        #pragma unroll
        for (int n = 0; n < 8; n++)
          acc[m][n] = __builtin_amdgcn_mfma_f32_16x16x32_bf16(
              a[m][k], bb[n][k], acc[m][n], 0, 0, 0);
    __builtin_amdgcn_s_setprio(0);

    // ---- next tile resident + own reads consumed -> single barrier ----
    asm volatile("s_waitcnt vmcnt(0)" ::: "memory");
    __builtin_amdgcn_s_barrier();
    __builtin_amdgcn_sched_barrier(0);
  }

  // epilogue: C/D layout col=lane&15, row=(lane>>4)*4+j
  const int crow = (lane >> 4) * 4;
  const int ccol = lane & 15;
  if (z == 0) {
    #pragma unroll
    for (int m = 0; m < 8; m++)
      #pragma unroll
      for (int n = 0; n < 8; n++)
        #pragma unroll
        for (int j = 0; j < 4; j++) {
          int64_t row = bm * 256 + wm * 128 + m * 16 + crow + j;
          int64_t col = bn * 256 + wn * 128 + n * 16 + ccol;
          storeC(&C0[row * (int64_t)ldc + col], acc[m][n][j]);
        }
  } else {
    #pragma unroll
    for (int m = 0; m < 8; m++)
      #pragma unroll
      for (int n = 0; n < 8; n++)
        #pragma unroll
        for (int j = 0; j < 4; j++) {
          int64_t row = bm * 256 + wm * 128 + m * 16 + crow + j;
          int64_t col = bn * 256 + wn * 128 + n * 16 + ccol;
          storeC(&C1[row * (int64_t)ldc + col], acc[m][n][j]);
        }
  }
}

// ---------------------------------------------------------------------------
// Row softmax IN PLACE: fp16 raw scores [rows x 4096] -> normalized bf16 P.
// ---------------------------------------------------------------------------
__global__ __launch_bounds__(256)
void softmax_rows(__half* __restrict__ SP)
{
  const int64_t row = blockIdx.x;
  __half* s = SP + row * 4096;
  bf16_t* p = (bf16_t*)s;
  const int tid = threadIdx.x;
  const float scale = 0.03125f;  // 1/sqrt(1024)

  float v[16];
  float vmax = -3.4e38f;
  #pragma unroll
  for (int i = 0; i < 4; i++) {
    uint2 raw = *(const uint2*)(s + i * 1024 + tid * 4);
    __half2 h01 = __builtin_bit_cast(__half2, raw.x);
    __half2 h23 = __builtin_bit_cast(__half2, raw.y);
    float2 f01 = __half22float2(h01);
    float2 f23 = __half22float2(h23);
    v[i * 4 + 0] = f01.x * scale;
    v[i * 4 + 1] = f01.y * scale;
    v[i * 4 + 2] = f23.x * scale;
    v[i * 4 + 3] = f23.y * scale;
    vmax = fmaxf(vmax, fmaxf(fmaxf(v[i*4+0], v[i*4+1]),
                             fmaxf(v[i*4+2], v[i*4+3])));
  }
  #pragma unroll
  for (int o = 32; o > 0; o >>= 1) vmax = fmaxf(vmax, __shfl_xor(vmax, o));
  __shared__ float redm[4];
  __shared__ float reds[4];
  if ((tid & 63) == 0) redm[tid >> 6] = vmax;
  __syncthreads();
  vmax = fmaxf(fmaxf(redm[0], redm[1]), fmaxf(redm[2], redm[3]));

  float lsum = 0.f;
  #pragma unroll
  for (int i = 0; i < 16; i++) {
    v[i] = __expf(v[i] - vmax);
    lsum += v[i];
  }
  #pragma unroll
  for (int o = 32; o > 0; o >>= 1) lsum += __shfl_xor(lsum, o);
  if ((tid & 63) == 0) reds[tid >> 6] = lsum;
  __syncthreads();
  lsum = (reds[0] + reds[1]) + (reds[2] + reds[3]);
  const float inv = 1.0f / lsum;

  #pragma unroll
  for (int i = 0; i < 4; i++) {
    uint32_t lo = ((uint32_t)f2bf_bits(v[i*4+1] * inv) << 16) | f2bf_bits(v[i*4+0] * inv);
    uint32_t hi = ((uint32_t)f2bf_bits(v[i*4+3] * inv) << 16) | f2bf_bits(v[i*4+2] * inv);
    *(uint2*)(p + i * 1024 + tid * 4) = make_uint2(lo, hi);
  }
}

// ---------------------------------------------------------------------------
// out[i] += (float)partial_fp16[i]  (split-K reduce)
// ---------------------------------------------------------------------------
__global__ __launch_bounds__(256)
void addk_h4(float4* __restrict__ o, const uint2* __restrict__ a, int64_t n4)
{
  for (int64_t i = (int64_t)blockIdx.x * blockDim.x + threadIdx.x; i < n4;
       i += (int64_t)gridDim.x * blockDim.x) {
    float4 x = o[i];
    uint2 raw = a[i];
    __half2 h01 = __builtin_bit_cast(__half2, raw.x);
    __half2 h23 = __builtin_bit_cast(__half2, raw.y);
    float2 f01 = __half22float2(h01);
    float2 f23 = __half22float2(h23);
    x.x += f01.x; x.y += f01.y; x.z += f23.x; x.w += f23.y;
    o[i] = x;
  }
}

// ---------------------------------------------------------------------------
// ws layout (112 MiB):
//   [0,   64M): S/P fp16->bf16 [8192 x 4096]
//               overlapped early: xb [0,16M), wqkb [16M,20M), wvb [20M,22M)
//   [64M, 96M): qk bf16 [8192 x 2048] (Q|K); dead after S -> reused as
//               PV fp16 split-K partial pk16 [8192 x 1024] (16 MiB)
//   [96M,112M): vt bf16 [1024 x 8192]
// ---------------------------------------------------------------------------
extern "C" void kernel_launch(void* const* d_in, const int* in_sizes, int n_in,
                              void* d_out, int out_size, void* d_ws, size_t ws_size,
                              hipStream_t stream) {
  const float* x  = (const float*)d_in[0];
  const float* wq = (const float*)d_in[1];
  const float* wk = (const float*)d_in[2];
  const float* wv = (const float*)d_in[3];
  float* out = (float*)d_out;

  char* ws = (char*)d_ws;
  bf16_t* xb   = (bf16_t*)ws;
  bf16_t* wqkb = (bf16_t*)(ws + (16LL << 20));
  bf16_t* wvb  = (bf16_t*)(ws + (20LL << 20));
  __half* S    = (__half*)ws;
  bf16_t* qk   = (bf16_t*)(ws + (64LL << 20));
  __half* pk16 = (__half*)(ws + (64LL << 20));  // PV split-K partial (16 MiB)
  bf16_t* vt   = (bf16_t*)(ws + (96LL << 20));

  const int NO_BATCH = 1 << 30;

  convert_all<<<2048, 256, 0, stream>>>(x, wq, wk, wv, xb, wqkb, wvb);

  // qk[8192 x 2048] = xb * wqkb^T   (fat 256^2, grid 256 blocks)
  gemm_fat<bf16_t, bf16_t><<<dim3(32, 8, 1), 256, 0, stream>>>(
      xb, wqkb, qk, qk, 1024, 1024, 1024, 2048, 0, NO_BATCH, 0, 0);

  // vt[1024 x 8192] = wvb * xb^T   (128^2, 512 blocks)
  gemm128<bf16_t, bf16_t><<<dim3(8, 64, 1), 256, 0, stream>>>(
      wvb, xb, vt, vt, 1024, 1024, 1024, 8192, 0, NO_BATCH, 0, 0);

  // S[8192 x 4096] = Q * K_b^T (raw fp16), batch b = bm/16
  gemm_fat<__half, __half><<<dim3(32, 16, 1), 256, 0, stream>>>(
      qk, qk + 1024, S, S, 1024, 2048, 2048, 4096, 4096LL * 2048, 16, 0, 0);

  softmax_rows<<<8192, 256, 0, stream>>>(S);

  // out[8192 x 1024] = P * V_b^T, split-K (z=0 -> out f32, z=1 -> pk16 fp16)
  gemm_fat<float, __half><<<dim3(32, 4, 2), 256, 0, stream>>>(
      (const bf16_t*)S, vt, out, pk16, 2048, 4096, 8192, 1024,
      4096, 16, 2048, 2048);

  addk_h4<<<2048, 256, 0, stream>>>((float4*)out, (const uint2*)pk16,
                                    8192LL * 1024 / 4);
}